// Round 1
// 349.434 us; speedup vs baseline: 1.1109x; 1.1109x over previous
//
#include <hip/hip_runtime.h>
#include <math.h>

#define NSRC 50000
#define NDST 50000
#define NE   500000
#define HD   128
#define EDIM 32
#define LN_EPS 1e-5f

typedef __attribute__((ext_vector_type(8))) short short8;   // 8 bf16 = 4 VGPR
typedef __attribute__((ext_vector_type(4))) float f32x4;
typedef unsigned short u16;

#define TL2E 2.8853900817779268f   /* 2*log2(e) */
#define L2E  1.4426950408889634f   /* log2(e)   */

__device__ __forceinline__ float EXP2(float x) {
#if __has_builtin(__builtin_amdgcn_exp2f)
    return __builtin_amdgcn_exp2f(x);
#else
    return exp2f(x);
#endif
}
__device__ __forceinline__ float RCP(float x) {
#if __has_builtin(__builtin_amdgcn_rcpf)
    return __builtin_amdgcn_rcpf(x);
#else
    return 1.f / x;
#endif
}
__device__ __forceinline__ u16 f2b(float x) {           // f32 -> bf16 RNE
    unsigned u = __float_as_uint(x);
    return (u16)((u + 0x7FFFu + ((u >> 16) & 1u)) >> 16);
}
__device__ __forceinline__ float b2f(u16 h) {
    return __uint_as_float(((unsigned)h) << 16);
}
__device__ __forceinline__ short8 ld8(const u16* p) { return *(const short8*)p; }

// ---------------------------------------------------------------------------
// fold1: Wsm = Wsrc@Wmsg, bsm = bsrc@Wmsg + bmsg, WeMsg = We@Wmsg, c2 = be@Wmsg
// ---------------------------------------------------------------------------
__global__ __launch_bounds__(128) void fold1_kernel(
    const float* __restrict__ Wsrc, const float* __restrict__ bsrc,
    const float* __restrict__ We,   const float* __restrict__ be,
    const float* __restrict__ Wmsg, const float* __restrict__ bmsg,
    float* __restrict__ Wsm, float* __restrict__ bsm,
    float* __restrict__ WeMsg, float* __restrict__ c2)
{
    const int j = threadIdx.x;
    const int r = blockIdx.x;
    float s = 0.f;
    if (r < 128) {
        for (int k = 0; k < 128; ++k) s += Wsrc[r*HD + k] * Wmsg[k*HD + j];
        Wsm[r*HD + j] = s;
    } else if (r < 160) {
        const int rr = r - 128;
        for (int k = 0; k < 128; ++k) s += We[rr*HD + k] * Wmsg[k*HD + j];
        WeMsg[rr*HD + j] = s;
    } else if (r == 160) {
        for (int k = 0; k < 128; ++k) s += bsrc[k] * Wmsg[k*HD + j];
        bsm[j] = s + bmsg[j];
    } else {
        for (int k = 0; k < 128; ++k) s += be[k] * Wmsg[k*HD + j];
        c2[j] = s;
    }
}

// ---------------------------------------------------------------------------
// fold2: W3 = WeMsg@Wout2; bias2 = bout + c2@Wout2; Wout1p = Wout1 + I
// ---------------------------------------------------------------------------
__global__ __launch_bounds__(128) void fold2_kernel(
    const float* __restrict__ WeMsg, const float* __restrict__ c2,
    const float* __restrict__ Wout, const float* __restrict__ bout,
    float* __restrict__ W3, float* __restrict__ bias2,
    float* __restrict__ Wout1p)
{
    const int j = threadIdx.x;
    const int r = blockIdx.x;
    const float* Wout2 = Wout + HD*HD;
    if (r < 32) {
        float s = 0.f;
        for (int k = 0; k < 128; ++k) s += WeMsg[r*HD + k] * Wout2[k*HD + j];
        W3[r*HD + j] = s;
    } else if (r == 32) {
        float s = 0.f;
        for (int k = 0; k < 128; ++k) s += c2[k] * Wout2[k*HD + j];
        bias2[j] = s + bout[j];
    } else {
        const int rr = r - 33;
        Wout1p[rr*HD + j] = Wout[rr*HD + j] + ((rr == j) ? 1.f : 0.f);
    }
}

// ---------------------------------------------------------------------------
// pack_all: pack f32 [K x 128] weights into bf16 MFMA B-fragment layout.
// Wsrc/Wdst/We get pre-scaled by 2*log2(e): their outputs feed the tanh-dot
// paths, refactored as sum(w*tanh(x)) = sum(w) - 2*sum(w * rcp(exp2(c*x)+1)).
// blocks: Wsrc 0-31, Wdst 32-63, Wsm 64-95, Wout1p 96-127, Wout2 128-159,
//         We 160-167 (K=32), W3 168-175 (K=32). 64 threads/block.
// ---------------------------------------------------------------------------
__global__ __launch_bounds__(64) void pack_all_kernel(
    const float* __restrict__ Wsrc, const float* __restrict__ Wdst,
    const float* __restrict__ Wsm,  const float* __restrict__ Wout1p,
    const float* __restrict__ Wout2,const float* __restrict__ We,
    const float* __restrict__ W3,
    u16* __restrict__ Wsrc_pk, u16* __restrict__ Wdst_pk,
    u16* __restrict__ Wsm_pk,  u16* __restrict__ W1_pk,
    u16* __restrict__ W2_pk,   u16* __restrict__ We_pk,
    u16* __restrict__ W3_pk)
{
    const int b = blockIdx.x;
    const int lane = threadIdx.x;
    const float* src; u16* dst; int lb; float scl = 1.f;
    if      (b < 32)  { src = Wsrc;   dst = Wsrc_pk; lb = b;       scl = TL2E; }
    else if (b < 64)  { src = Wdst;   dst = Wdst_pk; lb = b - 32;  scl = TL2E; }
    else if (b < 96)  { src = Wsm;    dst = Wsm_pk;  lb = b - 64; }
    else if (b < 128) { src = Wout1p; dst = W1_pk;   lb = b - 96; }
    else if (b < 160) { src = Wout2;  dst = W2_pk;   lb = b - 128; }
    else if (b < 168) { src = We;     dst = We_pk;   lb = b - 160; scl = TL2E; }
    else              { src = W3;     dst = W3_pk;   lb = b - 168; }
    const int kc = lb >> 3, t = lb & 7;
    const int ln = lane & 15, quad = lane >> 4;
    u16 tmp[8];
#pragma unroll
    for (int j = 0; j < 8; ++j)
        tmp[j] = f2b(src[(kc*32 + quad*8 + j)*HD + t*16 + ln] * scl);
    *(short8*)(dst + (size_t)(lb*64 + lane)*8) = *(short8*)tmp;
}

// ---------------------------------------------------------------------------
// convert: f32 -> bf16 for src_x, dst_x, edge_attr (4 elems/thread)
// ---------------------------------------------------------------------------
__global__ __launch_bounds__(256) void convert_kernel(
    const float* __restrict__ sx, const float* __restrict__ dx,
    const float* __restrict__ ea,
    u16* __restrict__ sxb, u16* __restrict__ dxb, u16* __restrict__ eab)
{
    const int n0 = NSRC*HD/4, n1 = n0 + NDST*HD/4, n2 = n1 + NE*EDIM/4;
    int i = blockIdx.x * 256 + threadIdx.x;
    const float4* s4; u16* d; int base;
    if (i < n0)      { s4 = (const float4*)sx; d = sxb; base = i; }
    else if (i < n1) { s4 = (const float4*)dx; d = dxb; base = i - n0; }
    else if (i < n2) { s4 = (const float4*)ea; d = eab; base = i - n1; }
    else return;
    float4 v = s4[base];
    u16 o[4] = { f2b(v.x), f2b(v.y), f2b(v.z), f2b(v.w) };
    *(ushort4*)(d + (size_t)base*4) = *(ushort4*)o;
}

// ---------------------------------------------------------------------------
// node_gemm: per 16 src rows (1 wave): s1 = tanh-dot via
//   s1 = sum(wa1) - 2 * sum(wa1 * rcp(exp2(2log2e*(x@Wsrc+bsrc)) + 1))
// (Wsrc_pk pre-scaled; bsrc scaled at load, folded into MFMA C-init), and
// srcmsgb = bf16(sxb@Wsm + bsm) (bsm folded into C-init).
// ---------------------------------------------------------------------------
__global__ __launch_bounds__(256) void node_gemm_kernel(
    const u16* __restrict__ sxb, const u16* __restrict__ Wsrc_pk,
    const u16* __restrict__ Wsm_pk, const float* __restrict__ bsrc,
    const float* __restrict__ bsm, const float* __restrict__ wa1,
    float* __restrict__ s1, u16* __restrict__ srcmsgb)
{
    __shared__ u16 lds[4 * 16 * HD];     // 16 KB, one 16x128 slab per wave
    const int t = threadIdx.x;
    const int w = t >> 6, lane = t & 63;
    const int ln = lane & 15, quad = lane >> 4;
    int row0 = (blockIdx.x * 4 + w) * 16;
    if (row0 > NSRC - 16) row0 = NSRC - 16;      // clamp (dup writes benign)

    short8 a[4];
#pragma unroll
    for (int kc = 0; kc < 4; ++kc)
        a[kc] = ld8(sxb + (size_t)(row0 + ln)*HD + kc*32 + quad*8);

    // ---- s1 path
    float v[4] = {0.f, 0.f, 0.f, 0.f};
    float ws = 0.f;
#pragma unroll
    for (int tt = 0; tt < 8; ++tt) {
        const float bb = bsrc[tt*16 + ln] * TL2E;
        const float ww = wa1[tt*16 + ln];
        f32x4 acc = {bb, bb, bb, bb};
#pragma unroll
        for (int kc = 0; kc < 4; ++kc) {
            short8 b = ld8(Wsrc_pk + (size_t)((kc*8 + tt)*64 + lane)*8);
            acc = __builtin_amdgcn_mfma_f32_16x16x32_bf16(a[kc], b, acc, 0, 0, 0);
        }
        ws += ww;
#pragma unroll
        for (int r = 0; r < 4; ++r)
            v[r] = fmaf(ww, RCP(EXP2(acc[r]) + 1.f), v[r]);
    }
#pragma unroll
    for (int off = 8; off >= 1; off >>= 1) {
        ws += __shfl_xor(ws, off);
#pragma unroll
        for (int r = 0; r < 4; ++r) v[r] += __shfl_xor(v[r], off);
    }
    if (ln == 0) {
#pragma unroll
        for (int r = 0; r < 4; ++r)
            s1[row0 + quad*4 + r] = fmaf(-2.f, v[r], ws);
    }

    // ---- srcmsg path
#pragma unroll
    for (int tt = 0; tt < 8; ++tt) {
        const float bs = bsm[tt*16 + ln];
        f32x4 acc = {bs, bs, bs, bs};
#pragma unroll
        for (int kc = 0; kc < 4; ++kc) {
            short8 b = ld8(Wsm_pk + (size_t)((kc*8 + tt)*64 + lane)*8);
            acc = __builtin_amdgcn_mfma_f32_16x16x32_bf16(a[kc], b, acc, 0, 0, 0);
        }
#pragma unroll
        for (int r = 0; r < 4; ++r)
            lds[w*2048 + (quad*4 + r)*HD + tt*16 + ln] = f2b(acc[r]);
    }
    __syncthreads();
#pragma unroll
    for (int r = 0; r < 4; ++r) {
        int idx = r*512 + lane*8;
        short8 val = *(short8*)(lds + w*2048 + idx);
        int row = idx >> 7, col = idx & 127;
        *(short8*)(srcmsgb + (size_t)(row0 + row)*HD + col) = val;
    }
}

// ---------------------------------------------------------------------------
// dst_gemm: s2 tanh-dot (refactored form) per 16 rows / wave
// ---------------------------------------------------------------------------
__global__ __launch_bounds__(256) void dst_gemm_kernel(
    const u16* __restrict__ dxb, const u16* __restrict__ Wdst_pk,
    const float* __restrict__ bdst, const float* __restrict__ wa2,
    float* __restrict__ s2)
{
    const int t = threadIdx.x;
    const int w = t >> 6, lane = t & 63;
    const int ln = lane & 15, quad = lane >> 4;
    int row0 = (blockIdx.x * 4 + w) * 16;
    if (row0 > NDST - 16) row0 = NDST - 16;

    short8 a[4];
#pragma unroll
    for (int kc = 0; kc < 4; ++kc)
        a[kc] = ld8(dxb + (size_t)(row0 + ln)*HD + kc*32 + quad*8);

    float v[4] = {0.f, 0.f, 0.f, 0.f};
    float ws = 0.f;
#pragma unroll
    for (int tt = 0; tt < 8; ++tt) {
        const float bb = bdst[tt*16 + ln] * TL2E;
        const float ww = wa2[tt*16 + ln];
        f32x4 acc = {bb, bb, bb, bb};
#pragma unroll
        for (int kc = 0; kc < 4; ++kc) {
            short8 b = ld8(Wdst_pk + (size_t)((kc*8 + tt)*64 + lane)*8);
            acc = __builtin_amdgcn_mfma_f32_16x16x32_bf16(a[kc], b, acc, 0, 0, 0);
        }
        ws += ww;
#pragma unroll
        for (int r = 0; r < 4; ++r)
            v[r] = fmaf(ww, RCP(EXP2(acc[r]) + 1.f), v[r]);
    }
#pragma unroll
    for (int off = 8; off >= 1; off >>= 1) {
        ws += __shfl_xor(ws, off);
#pragma unroll
        for (int r = 0; r < 4; ++r) v[r] += __shfl_xor(v[r], off);
    }
    if (ln == 0) {
#pragma unroll
        for (int r = 0; r < 4; ++r)
            s2[row0 + quad*4 + r] = fmaf(-2.f, v[r], ws);
    }
}

// ---------------------------------------------------------------------------
// CSR build
// ---------------------------------------------------------------------------
__global__ void hist_kernel(const int* __restrict__ ei, int* __restrict__ cnt)
{
    int e = blockIdx.x * 256 + threadIdx.x;
    if (e < NE) atomicAdd(&cnt[ei[NE + e]], 1);
}

__global__ __launch_bounds__(1024) void scan1_kernel(
    const int* __restrict__ cnt, int* __restrict__ excl, int* __restrict__ bsum)
{
    __shared__ int buf[1024];
    const int t = threadIdx.x;
    const int i = blockIdx.x * 1024 + t;
    int v = (i < NDST) ? cnt[i] : 0;
    buf[t] = v;
    __syncthreads();
    for (int off = 1; off < 1024; off <<= 1) {
        int tv = (t >= off) ? buf[t - off] : 0;
        __syncthreads();
        buf[t] += tv;
        __syncthreads();
    }
    if (i < NDST) excl[i] = buf[t] - v;
    if (t == 1023) bsum[blockIdx.x] = buf[1023];
}

__global__ void scan2_kernel(int* __restrict__ bsum, int* __restrict__ rowptr)
{
    const int NB = (NDST + 1023) / 1024;
    const int t = threadIdx.x;
    int orig = (t < NB) ? bsum[t] : 0;
    int v = orig;
    for (int off = 1; off < 64; off <<= 1) {
        int u = __shfl_up(v, off);
        if (t >= off) v += u;
    }
    int total = __shfl(v, 63);
    if (t < NB) bsum[t] = v - orig;
    if (t == 0) rowptr[NDST] = total;
}

__global__ void scan3_kernel(const int* __restrict__ bsum,
                             int* __restrict__ rowptr, int* __restrict__ cursor)
{
    int i = blockIdx.x * 256 + threadIdx.x;
    if (i < NDST) {
        int v = rowptr[i] + bsum[i >> 10];
        rowptr[i] = v;
        cursor[i] = v;
    }
}

// ---------------------------------------------------------------------------
// edge_score_mfma: 16 edges / wave. Tanh-dot in refactored exp2/rcp form;
// bias folded into MFMA C-init; score written in log2-domain (softmax
// invariant). FUSED SCATTER: claims CSR slot via atomicAdd(cursor) and
// writes one aligned int4 {src, e, score_bits, 0} -- replaces the old
// scatter_kernel + epos + score_s round-trips.
// ---------------------------------------------------------------------------
__global__ __launch_bounds__(256) void edge_score_mfma_kernel(
    const int* __restrict__ ei, const u16* __restrict__ eab,
    const u16* __restrict__ We_pk, const float* __restrict__ be,
    const float* __restrict__ wattn, const float* __restrict__ battn,
    const float* __restrict__ s1, const float* __restrict__ s2,
    int* __restrict__ cursor, int4* __restrict__ ev16)
{
    const int t = threadIdx.x;
    const int w = t >> 6, lane = t & 63;
    const int ln = lane & 15, quad = lane >> 4;
    const int e0 = (blockIdx.x * 4 + w) * 16;
    if (e0 >= NE) return;                  // NE%16==0, no partial tiles

    short8 a = ld8(eab + (size_t)(e0 + ln)*EDIM + quad*8);
    const float* wa3 = wattn + 2*HD;

    float v[4] = {0.f, 0.f, 0.f, 0.f};
    float ws = 0.f;
#pragma unroll
    for (int tt = 0; tt < 8; ++tt) {
        const float bb = be[tt*16 + ln] * TL2E;
        const float ww = wa3[tt*16 + ln];
        f32x4 acc = {bb, bb, bb, bb};
        short8 b = ld8(We_pk + (size_t)(tt*64 + lane)*8);
        acc = __builtin_amdgcn_mfma_f32_16x16x32_bf16(a, b, acc, 0, 0, 0);
        ws += ww;
#pragma unroll
        for (int r = 0; r < 4; ++r)
            v[r] = fmaf(ww, RCP(EXP2(acc[r]) + 1.f), v[r]);
    }
#pragma unroll
    for (int off = 8; off >= 1; off >>= 1) {
        ws += __shfl_xor(ws, off);
#pragma unroll
        for (int r = 0; r < 4; ++r) v[r] += __shfl_xor(v[r], off);
    }

    if (ln == 0) {
        const float b0 = battn[0];
        const int4 se4 = *(const int4*)(ei + e0 + quad*4);
        const int4 de4 = *(const int4*)(ei + NE + e0 + quad*4);
#pragma unroll
        for (int r = 0; r < 4; ++r) {
            const int e = e0 + quad*4 + r;
            const int srcn = ((const int*)&se4)[r];
            const int dstn = ((const int*)&de4)[r];
            float sc = (fmaf(-2.f, v[r], ws) + s1[srcn] + s2[dstn] + b0) * L2E;
            int pos = atomicAdd(&cursor[dstn], 1);
            ev16[pos] = make_int4(srcn, e, __float_as_int(sc), 0);
        }
    }
}

// ---------------------------------------------------------------------------
// dst_agg4: 1 wave per dst. Sequential ev16 reads (score in log2-domain ->
// raw v_exp); 4 edges in flight; 16 lanes x 16B cover one bf16 srcmsg row.
// Outputs aggSb (bf16 [NDST,128]) and weab (bf16 [NDST,32]).
// Empty dst: aggSb = bf16(-c2), weab = 0.
// ---------------------------------------------------------------------------
__global__ __launch_bounds__(256) void dst_agg4_kernel(
    const int4* __restrict__ ev16, const int* __restrict__ rowptr,
    const u16* __restrict__ srcmsgb, const u16* __restrict__ eab,
    const float* __restrict__ c2,
    u16* __restrict__ aggSb, u16* __restrict__ weab)
{
    const int lane = threadIdx.x & 63;
    const int d = blockIdx.x * 4 + (threadIdx.x >> 6);
    const int el = lane >> 4, c = lane & 15;
    const int start = rowptr[d], end = rowptr[d + 1];

    if (start == end) {
        if (el == 0) {
            u16 z[8];
#pragma unroll
            for (int j = 0; j < 8; ++j) z[j] = f2b(-c2[c*8 + j]);
            *(short8*)(aggSb + (size_t)d*HD + c*8) = *(short8*)z;
            if (c < 4) {
                u16 zz[8] = {0,0,0,0,0,0,0,0};
                *(short8*)(weab + (size_t)d*EDIM + c*8) = *(short8*)zz;
            }
        }
        return;
    }

    float m = -3.4e38f;
    for (int i = start + lane; i < end; i += 64)
        m = fmaxf(m, __int_as_float(ev16[i].z));
#pragma unroll
    for (int off = 32; off; off >>= 1) m = fmaxf(m, __shfl_xor(m, off));

    float s = 0.f;
    for (int i = start + lane; i < end; i += 64)
        s += EXP2(__int_as_float(ev16[i].z) - m);
#pragma unroll
    for (int off = 32; off; off >>= 1) s += __shfl_xor(s, off);
    const float inv = RCP(s);

    float acc[8] = {0,0,0,0,0,0,0,0};
    float wacc[8] = {0,0,0,0,0,0,0,0};
    for (int i0 = start; i0 < end; i0 += 4) {
        int i = i0 + el;
        bool val = (i < end);
        int ii = val ? i : start;
        int4 q = ev16[ii];
        float wgt = val ? EXP2(__int_as_float(q.z) - m) : 0.f;
        short8 sm = ld8(srcmsgb + (size_t)q.x*HD + c*8);
#pragma unroll
        for (int j = 0; j < 8; ++j) acc[j] += wgt * b2f(((u16*)&sm)[j]);
        if (c < 4) {
            short8 eav = ld8(eab + (size_t)q.y*EDIM + c*8);
#pragma unroll
            for (int j = 0; j < 8; ++j) wacc[j] += wgt * b2f(((u16*)&eav)[j]);
        }
    }
#pragma unroll
    for (int off = 16; off <= 32; off <<= 1) {
#pragma unroll
        for (int j = 0; j < 8; ++j) {
            acc[j]  += __shfl_xor(acc[j],  off);
            wacc[j] += __shfl_xor(wacc[j], off);
        }
    }
    if (el == 0) {
        u16 o[8];
#pragma unroll
        for (int j = 0; j < 8; ++j) o[j] = f2b(acc[j] * inv);
        *(short8*)(aggSb + (size_t)d*HD + c*8) = *(short8*)o;
        if (c < 4) {
            u16 o2[8];
#pragma unroll
            for (int j = 0; j < 8; ++j) o2[j] = f2b(wacc[j] * inv);
            *(short8*)(weab + (size_t)d*EDIM + c*8) = *(short8*)o2;
        }
    }
}

// ---------------------------------------------------------------------------
// final: out = LN(dxb@W1p + aggSb@Wout2 + weab@W3 + bias2) * gamma + beta
// per 16 dst rows / wave, 72 MFMA + LN epilogue. bias2 folded into C-init.
// ---------------------------------------------------------------------------
__global__ __launch_bounds__(256) void final_kernel(
    const u16* __restrict__ dxb, const u16* __restrict__ aggSb,
    const u16* __restrict__ weab,
    const u16* __restrict__ W1_pk, const u16* __restrict__ W2_pk,
    const u16* __restrict__ W3_pk, const float* __restrict__ bias2,
    const float* __restrict__ gamma, const float* __restrict__ beta,
    float* __restrict__ out)
{
    const int t = threadIdx.x;
    const int w = t >> 6, lane = t & 63;
    const int ln = lane & 15, quad = lane >> 4;
    int row0 = (blockIdx.x * 4 + w) * 16;
    if (row0 > NDST - 16) row0 = NDST - 16;

    short8 a1[4], a2[4], a3;
#pragma unroll
    for (int kc = 0; kc < 4; ++kc) {
        a1[kc] = ld8(dxb   + (size_t)(row0 + ln)*HD + kc*32 + quad*8);
        a2[kc] = ld8(aggSb + (size_t)(row0 + ln)*HD + kc*32 + quad*8);
    }
    a3 = ld8(weab + (size_t)(row0 + ln)*EDIM + quad*8);

    f32x4 accs[8];
#pragma unroll
    for (int tt = 0; tt < 8; ++tt) {
        const float bb = bias2[tt*16 + ln];
        f32x4 acc = {bb, bb, bb, bb};
#pragma unroll
        for (int kc = 0; kc < 4; ++kc) {
            short8 b = ld8(W1_pk + (size_t)((kc*8 + tt)*64 + lane)*8);
            acc = __builtin_amdgcn_mfma_f32_16x16x32_bf16(a1[kc], b, acc, 0, 0, 0);
        }
#pragma unroll
        for (int kc = 0; kc < 4; ++kc) {
            short8 b = ld8(W2_pk + (size_t)((kc*8 + tt)*64 + lane)*8);
            acc = __builtin_amdgcn_mfma_f32_16x16x32_bf16(a2[kc], b, acc, 0, 0, 0);
        }
        {
            short8 b = ld8(W3_pk + (size_t)(tt*64 + lane)*8);
            acc = __builtin_amdgcn_mfma_f32_16x16x32_bf16(a3, b, acc, 0, 0, 0);
        }
        accs[tt] = acc;
    }

    const float gl[8] = { gamma[ln], gamma[16+ln], gamma[32+ln], gamma[48+ln],
                          gamma[64+ln], gamma[80+ln], gamma[96+ln], gamma[112+ln] };
    const float bl[8] = { beta[ln], beta[16+ln], beta[32+ln], beta[48+ln],
                          beta[64+ln], beta[80+ln], beta[96+ln], beta[112+ln] };
#pragma unroll
    for (int r = 0; r < 4; ++r) {
        float s = 0.f, q = 0.f;
#pragma unroll
        for (int tt = 0; tt < 8; ++tt) {
            float u = accs[tt][r];
            s += u; q += u*u;
        }
#pragma unroll
        for (int off = 8; off >= 1; off >>= 1) {
            s += __shfl_xor(s, off);
            q += __shfl_xor(q, off);
        }
        const float mean = s * (1.f / HD);
        const float var  = q * (1.f / HD) - mean * mean;
        const float rstd = rsqrtf(var + LN_EPS);
        const int row = row0 + quad*4 + r;
#pragma unroll
        for (int tt = 0; tt < 8; ++tt)
            out[(size_t)row*HD + tt*16 + ln] =
                (accs[tt][r] - mean) * rstd * gl[tt] + bl[tt];
    }
}

// ---------------------------------------------------------------------------
extern "C" void kernel_launch(void* const* d_in, const int* in_sizes, int n_in,
                              void* d_out, int out_size, void* d_ws, size_t ws_size,
                              hipStream_t stream)
{
    const float* src_x = (const float*)d_in[0];
    const float* dst_x = (const float*)d_in[1];
    const int*   ei    = (const int*)d_in[2];
    const float* eattr = (const float*)d_in[3];
    const float* Wsrc  = (const float*)d_in[4];
    const float* bsrc  = (const float*)d_in[5];
    const float* Wdst  = (const float*)d_in[6];
    const float* bdst  = (const float*)d_in[7];
    const float* We    = (const float*)d_in[8];
    const float* be    = (const float*)d_in[9];
    const float* Wattn = (const float*)d_in[10];
    const float* battn = (const float*)d_in[11];
    const float* Wmsg  = (const float*)d_in[12];
    const float* bmsg  = (const float*)d_in[13];
    const float* Wout  = (const float*)d_in[14];
    const float* bout  = (const float*)d_in[15];
    const float* gamma = (const float*)d_in[16];
    const float* beta  = (const float*)d_in[17];
    float* out = (float*)d_out;

    float* ws = (float*)d_ws;
    u16* sxb     = (u16*)(ws + 0);            // 6.4M bf16
    u16* dxb     = (u16*)(ws + 3200000);      // 6.4M bf16
    u16* eab     = (u16*)(ws + 6400000);      // 16M bf16
    u16* srcmsgb = (u16*)(ws + 14400000);     // 6.4M bf16
    u16* aggSb   = (u16*)(ws + 17600000);     // 6.4M bf16
    u16* weab    = (u16*)(ws + 20800000);     // 1.6M bf16
    float* s1    = ws + 21600000;             // 50048
    float* s2    = ws + 21650048;             // 50048
    float* Wsm   = ws + 21700096;             // 16384
    float* bsm   = ws + 21716480;             // 128
    float* WeMsg = ws + 21716608;             // 4096
    float* c2    = ws + 21720704;             // 128
    float* W3    = ws + 21720832;             // 4096
    float* bias2 = ws + 21724928;             // 128
    float* Wout1p= ws + 21725056;             // 16384
    u16* Wsrc_pk = (u16*)(ws + 21741440);     // 16384 u16
    u16* Wdst_pk = (u16*)(ws + 21749632);
    u16* Wsm_pk  = (u16*)(ws + 21757824);
    u16* W1_pk   = (u16*)(ws + 21766016);
    u16* W2_pk   = (u16*)(ws + 21774208);
    u16* We_pk   = (u16*)(ws + 21782400);     // 4096 u16
    u16* W3_pk   = (u16*)(ws + 21784448);     // 4096 u16
    int* rowptr  = (int*)(ws + 21786496);     // 50016
    int* cursor  = rowptr + 50016;            // 50016
    int* bsum    = cursor + 50016;            // 64
    int4* ev16   = (int4*)(bsum + 64);        // 500000 int4 (16B-aligned)

    hipMemsetAsync(cursor, 0, NDST * sizeof(int), stream);

    fold1_kernel<<<162, 128, 0, stream>>>(Wsrc, bsrc, We, be, Wmsg, bmsg,
                                          Wsm, bsm, WeMsg, c2);
    fold2_kernel<<<161, 128, 0, stream>>>(WeMsg, c2, Wout, bout, W3, bias2, Wout1p);
    pack_all_kernel<<<176, 64, 0, stream>>>(Wsrc, Wdst, Wsm, Wout1p, Wout + HD*HD,
                                            We, W3,
                                            Wsrc_pk, Wdst_pk, Wsm_pk, W1_pk,
                                            W2_pk, We_pk, W3_pk);
    convert_kernel<<<28125, 256, 0, stream>>>(src_x, dst_x, eattr, sxb, dxb, eab);

    const int g16 = (NSRC/16 + 3) / 4;        // 782 blocks, 4 waves each

    node_gemm_kernel<<<g16, 256, 0, stream>>>(sxb, Wsrc_pk, Wsm_pk, bsrc, bsm,
                                              Wattn, s1, srcmsgb);
    dst_gemm_kernel<<<g16, 256, 0, stream>>>(dxb, Wdst_pk, bdst, Wattn + HD, s2);

    hist_kernel<<<(NE + 255) / 256, 256, 0, stream>>>(ei, cursor);
    scan1_kernel<<<(NDST + 1023) / 1024, 1024, 0, stream>>>(cursor, rowptr, bsum);
    scan2_kernel<<<1, 64, 0, stream>>>(bsum, rowptr);
    scan3_kernel<<<(NDST + 255) / 256, 256, 0, stream>>>(bsum, rowptr, cursor);

    edge_score_mfma_kernel<<<(NE/16 + 3) / 4, 256, 0, stream>>>(
        ei, eab, We_pk, be, Wattn, battn, s1, s2, cursor, ev16);

    dst_agg4_kernel<<<NDST / 4, 256, 0, stream>>>(ev16, rowptr, srcmsgb,
                                                  eab, c2, aggSb, weab);

    final_kernel<<<g16, 256, 0, stream>>>(dxb, aggSb, weab, W1_pk, W2_pk, W3_pk,
                                          bias2, gamma, beta, out);
}

// Round 2
// 337.617 us; speedup vs baseline: 1.1498x; 1.0350x over previous
//
#include <hip/hip_runtime.h>
#include <math.h>

#define NSRC 50000
#define NDST 50000
#define NE   500000
#define HD   128
#define EDIM 32
#define LN_EPS 1e-5f

typedef __attribute__((ext_vector_type(8))) short short8;   // 8 bf16 = 4 VGPR
typedef __attribute__((ext_vector_type(4))) float f32x4;
typedef unsigned short u16;

#define TL2E 2.8853900817779268f   /* 2*log2(e) */
#define L2E  1.4426950408889634f   /* log2(e)   */

__device__ __forceinline__ float EXP2(float x) {
#if __has_builtin(__builtin_amdgcn_exp2f)
    return __builtin_amdgcn_exp2f(x);
#else
    return exp2f(x);
#endif
}
__device__ __forceinline__ float RCP(float x) {
#if __has_builtin(__builtin_amdgcn_rcpf)
    return __builtin_amdgcn_rcpf(x);
#else
    return 1.f / x;
#endif
}
__device__ __forceinline__ u16 f2b(float x) {           // f32 -> bf16 RNE
    unsigned u = __float_as_uint(x);
    return (u16)((u + 0x7FFFu + ((u >> 16) & 1u)) >> 16);
}
__device__ __forceinline__ float b2f(u16 h) {
    return __uint_as_float(((unsigned)h) << 16);
}
__device__ __forceinline__ short8 ld8(const u16* p) { return *(const short8*)p; }

// ---------------------------------------------------------------------------
// fold1: Wsm = Wsrc@Wmsg, bsm = bsrc@Wmsg + bmsg, WeMsg = We@Wmsg, c2 = be@Wmsg
// ---------------------------------------------------------------------------
__global__ __launch_bounds__(128) void fold1_kernel(
    const float* __restrict__ Wsrc, const float* __restrict__ bsrc,
    const float* __restrict__ We,   const float* __restrict__ be,
    const float* __restrict__ Wmsg, const float* __restrict__ bmsg,
    float* __restrict__ Wsm, float* __restrict__ bsm,
    float* __restrict__ WeMsg, float* __restrict__ c2)
{
    const int j = threadIdx.x;
    const int r = blockIdx.x;
    float s = 0.f;
    if (r < 128) {
        for (int k = 0; k < 128; ++k) s += Wsrc[r*HD + k] * Wmsg[k*HD + j];
        Wsm[r*HD + j] = s;
    } else if (r < 160) {
        const int rr = r - 128;
        for (int k = 0; k < 128; ++k) s += We[rr*HD + k] * Wmsg[k*HD + j];
        WeMsg[rr*HD + j] = s;
    } else if (r == 160) {
        for (int k = 0; k < 128; ++k) s += bsrc[k] * Wmsg[k*HD + j];
        bsm[j] = s + bmsg[j];
    } else {
        for (int k = 0; k < 128; ++k) s += be[k] * Wmsg[k*HD + j];
        c2[j] = s;
    }
}

// ---------------------------------------------------------------------------
// fold2: W3 = WeMsg@Wout2; bias2 = bout + c2@Wout2; Wout1p = Wout1 + I
// ---------------------------------------------------------------------------
__global__ __launch_bounds__(128) void fold2_kernel(
    const float* __restrict__ WeMsg, const float* __restrict__ c2,
    const float* __restrict__ Wout, const float* __restrict__ bout,
    float* __restrict__ W3, float* __restrict__ bias2,
    float* __restrict__ Wout1p)
{
    const int j = threadIdx.x;
    const int r = blockIdx.x;
    const float* Wout2 = Wout + HD*HD;
    if (r < 32) {
        float s = 0.f;
        for (int k = 0; k < 128; ++k) s += WeMsg[r*HD + k] * Wout2[k*HD + j];
        W3[r*HD + j] = s;
    } else if (r == 32) {
        float s = 0.f;
        for (int k = 0; k < 128; ++k) s += c2[k] * Wout2[k*HD + j];
        bias2[j] = s + bout[j];
    } else {
        const int rr = r - 33;
        Wout1p[rr*HD + j] = Wout[rr*HD + j] + ((rr == j) ? 1.f : 0.f);
    }
}

// ---------------------------------------------------------------------------
// pack_all: pack f32 [K x 128] weights into bf16 MFMA B-fragment layout.
// Wsrc/Wdst/We pre-scaled by 2*log2(e) (tanh-dot exp2/rcp refactor).
// ---------------------------------------------------------------------------
__global__ __launch_bounds__(64) void pack_all_kernel(
    const float* __restrict__ Wsrc, const float* __restrict__ Wdst,
    const float* __restrict__ Wsm,  const float* __restrict__ Wout1p,
    const float* __restrict__ Wout2,const float* __restrict__ We,
    const float* __restrict__ W3,
    u16* __restrict__ Wsrc_pk, u16* __restrict__ Wdst_pk,
    u16* __restrict__ Wsm_pk,  u16* __restrict__ W1_pk,
    u16* __restrict__ W2_pk,   u16* __restrict__ We_pk,
    u16* __restrict__ W3_pk)
{
    const int b = blockIdx.x;
    const int lane = threadIdx.x;
    const float* src; u16* dst; int lb; float scl = 1.f;
    if      (b < 32)  { src = Wsrc;   dst = Wsrc_pk; lb = b;       scl = TL2E; }
    else if (b < 64)  { src = Wdst;   dst = Wdst_pk; lb = b - 32;  scl = TL2E; }
    else if (b < 96)  { src = Wsm;    dst = Wsm_pk;  lb = b - 64; }
    else if (b < 128) { src = Wout1p; dst = W1_pk;   lb = b - 96; }
    else if (b < 160) { src = Wout2;  dst = W2_pk;   lb = b - 128; }
    else if (b < 168) { src = We;     dst = We_pk;   lb = b - 160; scl = TL2E; }
    else              { src = W3;     dst = W3_pk;   lb = b - 168; }
    const int kc = lb >> 3, t = lb & 7;
    const int ln = lane & 15, quad = lane >> 4;
    u16 tmp[8];
#pragma unroll
    for (int j = 0; j < 8; ++j)
        tmp[j] = f2b(src[(kc*32 + quad*8 + j)*HD + t*16 + ln] * scl);
    *(short8*)(dst + (size_t)(lb*64 + lane)*8) = *(short8*)tmp;
}

// ---------------------------------------------------------------------------
// node_gemm: per 16 src rows (1 wave). Reads src_x f32 directly (fused
// convert). s1 = sum(wa1) - 2*sum(wa1*rcp(exp2(..)+1));
// srcmsgb = bf16(x@Wsm + bsm).
// ---------------------------------------------------------------------------
__global__ __launch_bounds__(256) void node_gemm_kernel(
    const float* __restrict__ src_x, const u16* __restrict__ Wsrc_pk,
    const u16* __restrict__ Wsm_pk, const float* __restrict__ bsrc,
    const float* __restrict__ bsm, const float* __restrict__ wa1,
    float* __restrict__ s1, u16* __restrict__ srcmsgb)
{
    __shared__ u16 lds[4 * 16 * HD];     // 16 KB, one 16x128 slab per wave
    const int t = threadIdx.x;
    const int w = t >> 6, lane = t & 63;
    const int ln = lane & 15, quad = lane >> 4;
    int row0 = (blockIdx.x * 4 + w) * 16;
    if (row0 > NSRC - 16) row0 = NSRC - 16;      // clamp (dup writes benign)

    const float* rp = src_x + (size_t)(row0 + ln)*HD;
    short8 a[4];
#pragma unroll
    for (int kc = 0; kc < 4; ++kc) {
        float4 f0 = *(const float4*)(rp + kc*32 + quad*8);
        float4 f1 = *(const float4*)(rp + kc*32 + quad*8 + 4);
        u16 tb[8] = { f2b(f0.x), f2b(f0.y), f2b(f0.z), f2b(f0.w),
                      f2b(f1.x), f2b(f1.y), f2b(f1.z), f2b(f1.w) };
        a[kc] = *(short8*)tb;
    }

    // ---- s1 path
    float v[4] = {0.f, 0.f, 0.f, 0.f};
    float ws = 0.f;
#pragma unroll
    for (int tt = 0; tt < 8; ++tt) {
        const float bb = bsrc[tt*16 + ln] * TL2E;
        const float ww = wa1[tt*16 + ln];
        f32x4 acc = {bb, bb, bb, bb};
#pragma unroll
        for (int kc = 0; kc < 4; ++kc) {
            short8 b = ld8(Wsrc_pk + (size_t)((kc*8 + tt)*64 + lane)*8);
            acc = __builtin_amdgcn_mfma_f32_16x16x32_bf16(a[kc], b, acc, 0, 0, 0);
        }
        ws += ww;
#pragma unroll
        for (int r = 0; r < 4; ++r)
            v[r] = fmaf(ww, RCP(EXP2(acc[r]) + 1.f), v[r]);
    }
#pragma unroll
    for (int off = 8; off >= 1; off >>= 1) {
        ws += __shfl_xor(ws, off);
#pragma unroll
        for (int r = 0; r < 4; ++r) v[r] += __shfl_xor(v[r], off);
    }
    if (ln == 0) {
#pragma unroll
        for (int r = 0; r < 4; ++r)
            s1[row0 + quad*4 + r] = fmaf(-2.f, v[r], ws);
    }

    // ---- srcmsg path
#pragma unroll
    for (int tt = 0; tt < 8; ++tt) {
        const float bs = bsm[tt*16 + ln];
        f32x4 acc = {bs, bs, bs, bs};
#pragma unroll
        for (int kc = 0; kc < 4; ++kc) {
            short8 b = ld8(Wsm_pk + (size_t)((kc*8 + tt)*64 + lane)*8);
            acc = __builtin_amdgcn_mfma_f32_16x16x32_bf16(a[kc], b, acc, 0, 0, 0);
        }
#pragma unroll
        for (int r = 0; r < 4; ++r)
            lds[w*2048 + (quad*4 + r)*HD + tt*16 + ln] = f2b(acc[r]);
    }
    __syncthreads();
#pragma unroll
    for (int r = 0; r < 4; ++r) {
        int idx = r*512 + lane*8;
        short8 val = *(short8*)(lds + w*2048 + idx);
        int row = idx >> 7, col = idx & 127;
        *(short8*)(srcmsgb + (size_t)(row0 + row)*HD + col) = val;
    }
}

// ---------------------------------------------------------------------------
// dst_gemm: s2 tanh-dot (refactored) per 16 rows / wave; reads dst_x f32.
// ---------------------------------------------------------------------------
__global__ __launch_bounds__(256) void dst_gemm_kernel(
    const float* __restrict__ dst_x, const u16* __restrict__ Wdst_pk,
    const float* __restrict__ bdst, const float* __restrict__ wa2,
    float* __restrict__ s2)
{
    const int t = threadIdx.x;
    const int w = t >> 6, lane = t & 63;
    const int ln = lane & 15, quad = lane >> 4;
    int row0 = (blockIdx.x * 4 + w) * 16;
    if (row0 > NDST - 16) row0 = NDST - 16;

    const float* rp = dst_x + (size_t)(row0 + ln)*HD;
    short8 a[4];
#pragma unroll
    for (int kc = 0; kc < 4; ++kc) {
        float4 f0 = *(const float4*)(rp + kc*32 + quad*8);
        float4 f1 = *(const float4*)(rp + kc*32 + quad*8 + 4);
        u16 tb[8] = { f2b(f0.x), f2b(f0.y), f2b(f0.z), f2b(f0.w),
                      f2b(f1.x), f2b(f1.y), f2b(f1.z), f2b(f1.w) };
        a[kc] = *(short8*)tb;
    }

    float v[4] = {0.f, 0.f, 0.f, 0.f};
    float ws = 0.f;
#pragma unroll
    for (int tt = 0; tt < 8; ++tt) {
        const float bb = bdst[tt*16 + ln] * TL2E;
        const float ww = wa2[tt*16 + ln];
        f32x4 acc = {bb, bb, bb, bb};
#pragma unroll
        for (int kc = 0; kc < 4; ++kc) {
            short8 b = ld8(Wdst_pk + (size_t)((kc*8 + tt)*64 + lane)*8);
            acc = __builtin_amdgcn_mfma_f32_16x16x32_bf16(a[kc], b, acc, 0, 0, 0);
        }
        ws += ww;
#pragma unroll
        for (int r = 0; r < 4; ++r)
            v[r] = fmaf(ww, RCP(EXP2(acc[r]) + 1.f), v[r]);
    }
#pragma unroll
    for (int off = 8; off >= 1; off >>= 1) {
        ws += __shfl_xor(ws, off);
#pragma unroll
        for (int r = 0; r < 4; ++r) v[r] += __shfl_xor(v[r], off);
    }
    if (ln == 0) {
#pragma unroll
        for (int r = 0; r < 4; ++r)
            s2[row0 + quad*4 + r] = fmaf(-2.f, v[r], ws);
    }
}

// ---------------------------------------------------------------------------
// CSR build
// ---------------------------------------------------------------------------
__global__ void hist_kernel(const int* __restrict__ ei, int* __restrict__ cnt)
{
    int e = blockIdx.x * 256 + threadIdx.x;
    if (e < NE) atomicAdd(&cnt[ei[NE + e]], 1);
}

__global__ __launch_bounds__(1024) void scan1_kernel(
    const int* __restrict__ cnt, int* __restrict__ excl, int* __restrict__ bsum)
{
    __shared__ int buf[1024];
    const int t = threadIdx.x;
    const int i = blockIdx.x * 1024 + t;
    int v = (i < NDST) ? cnt[i] : 0;
    buf[t] = v;
    __syncthreads();
    for (int off = 1; off < 1024; off <<= 1) {
        int tv = (t >= off) ? buf[t - off] : 0;
        __syncthreads();
        buf[t] += tv;
        __syncthreads();
    }
    if (i < NDST) excl[i] = buf[t] - v;
    if (t == 1023) bsum[blockIdx.x] = buf[1023];
}

__global__ void scan2_kernel(int* __restrict__ bsum, int* __restrict__ rowptr)
{
    const int NB = (NDST + 1023) / 1024;
    const int t = threadIdx.x;
    int orig = (t < NB) ? bsum[t] : 0;
    int v = orig;
    for (int off = 1; off < 64; off <<= 1) {
        int u = __shfl_up(v, off);
        if (t >= off) v += u;
    }
    int total = __shfl(v, 63);
    if (t < NB) bsum[t] = v - orig;
    if (t == 0) rowptr[NDST] = total;
}

__global__ void scan3_kernel(const int* __restrict__ bsum,
                             int* __restrict__ rowptr, int* __restrict__ cursor)
{
    int i = blockIdx.x * 256 + threadIdx.x;
    if (i < NDST) {
        int v = rowptr[i] + bsum[i >> 10];
        rowptr[i] = v;
        cursor[i] = v;
    }
}

// ---------------------------------------------------------------------------
// edge_score: 16 edges / wave. Reads edge_attr f32 directly (fused convert).
// Tanh-dot in exp2/rcp form; score in log2-domain (no-max softmax is safe:
// |score| <= sum|wattn| + |battn| <= ~20). FUSED SCATTER: 16 leader lanes
// (quad 0) claim CSR slots; all 64 lanes scatter the bf16 ea row to eas[pos]
// (sequentially readable in dst_agg -> kills the 64B random-gather
// over-fetch). Record ev8 = {src, score} 8B.
// ---------------------------------------------------------------------------
__global__ __launch_bounds__(256) void edge_score_kernel(
    const int* __restrict__ ei, const float* __restrict__ eattr,
    const u16* __restrict__ We_pk, const float* __restrict__ be,
    const float* __restrict__ wattn, const float* __restrict__ battn,
    const float* __restrict__ s1, const float* __restrict__ s2,
    int* __restrict__ cursor, int2* __restrict__ ev8, u16* __restrict__ eas)
{
    const int t = threadIdx.x;
    const int w = t >> 6, lane = t & 63;
    const int ln = lane & 15, quad = lane >> 4;
    const int e0 = (blockIdx.x * 4 + w) * 16;
    if (e0 >= NE) return;                  // NE%16==0, no partial tiles

    const float* ap = eattr + (size_t)(e0 + ln)*EDIM + quad*8;
    float4 f0 = *(const float4*)(ap);
    float4 f1 = *(const float4*)(ap + 4);
    u16 ab[8] = { f2b(f0.x), f2b(f0.y), f2b(f0.z), f2b(f0.w),
                  f2b(f1.x), f2b(f1.y), f2b(f1.z), f2b(f1.w) };
    short8 a = *(short8*)ab;

    const float* wa3 = wattn + 2*HD;
    float v[4] = {0.f, 0.f, 0.f, 0.f};
    float ws = 0.f;
#pragma unroll
    for (int tt = 0; tt < 8; ++tt) {
        const float bb = be[tt*16 + ln] * TL2E;
        const float ww = wa3[tt*16 + ln];
        f32x4 acc = {bb, bb, bb, bb};
        short8 b = ld8(We_pk + (size_t)(tt*64 + lane)*8);
        acc = __builtin_amdgcn_mfma_f32_16x16x32_bf16(a, b, acc, 0, 0, 0);
        ws += ww;
#pragma unroll
        for (int r = 0; r < 4; ++r)
            v[r] = fmaf(ww, RCP(EXP2(acc[r]) + 1.f), v[r]);
    }
#pragma unroll
    for (int off = 8; off >= 1; off >>= 1) {
        ws += __shfl_xor(ws, off);
#pragma unroll
        for (int r = 0; r < 4; ++r) v[r] += __shfl_xor(v[r], off);
    }
    // after the ln-xor ladder every lane of quad q holds the full dots for
    // edges q*4+{0..3} in v[0..3]. Move edge (ln)'s dot to every lane:
    const int srcq = (ln >> 2) << 4;
    float sv0 = __shfl(v[0], srcq);
    float sv1 = __shfl(v[1], srcq);
    float sv2 = __shfl(v[2], srcq);
    float sv3 = __shfl(v[3], srcq);
    const int rr = ln & 3;
    float vlo = (rr & 1) ? sv1 : sv0;
    float vhi = (rr & 1) ? sv3 : sv2;
    float vv  = (rr & 2) ? vhi : vlo;

    int pos;
    if (quad == 0) {                       // 16 leader lanes, one per edge
        const int e = e0 + ln;
        const int srcn = ei[e];
        const int dstn = ei[NE + e];
        float sc = (fmaf(-2.f, vv, ws) + s1[srcn] + s2[dstn] + battn[0]) * L2E;
        pos = atomicAdd(&cursor[dstn], 1);
        ev8[pos] = make_int2(srcn, __float_as_int(sc));
    }
    pos = __shfl(pos, ln);                 // broadcast edge ln's slot
    *(short8*)(eas + (size_t)pos*EDIM + quad*8) = a;
}

// ---------------------------------------------------------------------------
// dst_agg: 1 wave per dst, SINGLE PASS (no-max softmax): accumulate
// unnormalized w=exp2(sc), sum(w), sum(w*msg), sum(w*ea); normalize by
// rcp at the end. 4 edges in flight (el groups); 16 lanes x 16B per msg row.
// ev8 reads sequential+prefetched; eas reads sequential; only the srcmsg
// row gather is data-dependent. Empty dst: aggSb=-c2, weab=0.
// ---------------------------------------------------------------------------
__global__ __launch_bounds__(256) void dst_agg_kernel(
    const int2* __restrict__ ev8, const u16* __restrict__ eas,
    const int* __restrict__ rowptr, const u16* __restrict__ srcmsgb,
    const float* __restrict__ c2,
    u16* __restrict__ aggSb, u16* __restrict__ weab)
{
    const int lane = threadIdx.x & 63;
    const int d = blockIdx.x * 4 + (threadIdx.x >> 6);
    const int el = lane >> 4, c = lane & 15;
    const int start = rowptr[d], end = rowptr[d + 1];

    if (start == end) {
        if (el == 0) {
            u16 z[8];
#pragma unroll
            for (int j = 0; j < 8; ++j) z[j] = f2b(-c2[c*8 + j]);
            *(short8*)(aggSb + (size_t)d*HD + c*8) = *(short8*)z;
            if (c < 4) {
                u16 zz[8] = {0,0,0,0,0,0,0,0};
                *(short8*)(weab + (size_t)d*EDIM + c*8) = *(short8*)zz;
            }
        }
        return;
    }

    float sacc = 0.f;
    float acc[8]  = {0,0,0,0,0,0,0,0};
    float wacc[8] = {0,0,0,0,0,0,0,0};

    int icur = start + el;
    bool vcur = (icur < end);
    int iicur = vcur ? icur : start;
    int2 q = ev8[iicur];

    for (int i0 = start; i0 < end; i0 += 4) {
        const float wgt = vcur ? EXP2(__int_as_float(q.y)) : 0.f;
        const int   srow = q.x;
        const int   iiuse = iicur;
        // prefetch next record (clamped; harmless over-read of ev8[start])
        const int inx = i0 + 4 + el;
        vcur = (inx < end);
        iicur = vcur ? inx : start;
        q = ev8[iicur];

        sacc += wgt;
        short8 sm = ld8(srcmsgb + (size_t)srow*HD + c*8);
#pragma unroll
        for (int j = 0; j < 8; ++j)
            acc[j] = fmaf(wgt, b2f(((u16*)&sm)[j]), acc[j]);
        if (c < 4) {
            short8 eav = ld8(eas + (size_t)iiuse*EDIM + c*8);
#pragma unroll
            for (int j = 0; j < 8; ++j)
                wacc[j] = fmaf(wgt, b2f(((u16*)&eav)[j]), wacc[j]);
        }
    }
#pragma unroll
    for (int off = 16; off <= 32; off <<= 1) {
        sacc += __shfl_xor(sacc, off);
#pragma unroll
        for (int j = 0; j < 8; ++j) {
            acc[j]  += __shfl_xor(acc[j],  off);
            wacc[j] += __shfl_xor(wacc[j], off);
        }
    }
    const float inv = RCP(sacc);
    if (el == 0) {
        u16 o[8];
#pragma unroll
        for (int j = 0; j < 8; ++j) o[j] = f2b(acc[j] * inv);
        *(short8*)(aggSb + (size_t)d*HD + c*8) = *(short8*)o;
        if (c < 4) {
            u16 o2[8];
#pragma unroll
            for (int j = 0; j < 8; ++j) o2[j] = f2b(wacc[j] * inv);
            *(short8*)(weab + (size_t)d*EDIM + c*8) = *(short8*)o2;
        }
    }
}

// ---------------------------------------------------------------------------
// final: out = LN(dst_x@W1p + aggSb@Wout2 + weab@W3 + bias2) * gamma + beta
// per 16 dst rows / wave; dst_x read f32 + converted in-reg.
// ---------------------------------------------------------------------------
__global__ __launch_bounds__(256) void final_kernel(
    const float* __restrict__ dst_x, const u16* __restrict__ aggSb,
    const u16* __restrict__ weab,
    const u16* __restrict__ W1_pk, const u16* __restrict__ W2_pk,
    const u16* __restrict__ W3_pk, const float* __restrict__ bias2,
    const float* __restrict__ gamma, const float* __restrict__ beta,
    float* __restrict__ out)
{
    const int t = threadIdx.x;
    const int w = t >> 6, lane = t & 63;
    const int ln = lane & 15, quad = lane >> 4;
    int row0 = (blockIdx.x * 4 + w) * 16;
    if (row0 > NDST - 16) row0 = NDST - 16;

    const float* rp = dst_x + (size_t)(row0 + ln)*HD;
    short8 a1[4], a2[4], a3;
#pragma unroll
    for (int kc = 0; kc < 4; ++kc) {
        float4 f0 = *(const float4*)(rp + kc*32 + quad*8);
        float4 f1 = *(const float4*)(rp + kc*32 + quad*8 + 4);
        u16 tb[8] = { f2b(f0.x), f2b(f0.y), f2b(f0.z), f2b(f0.w),
                      f2b(f1.x), f2b(f1.y), f2b(f1.z), f2b(f1.w) };
        a1[kc] = *(short8*)tb;
        a2[kc] = ld8(aggSb + (size_t)(row0 + ln)*HD + kc*32 + quad*8);
    }
    a3 = ld8(weab + (size_t)(row0 + ln)*EDIM + quad*8);

    f32x4 accs[8];
#pragma unroll
    for (int tt = 0; tt < 8; ++tt) {
        const float bb = bias2[tt*16 + ln];
        f32x4 acc = {bb, bb, bb, bb};
#pragma unroll
        for (int kc = 0; kc < 4; ++kc) {
            short8 b = ld8(W1_pk + (size_t)((kc*8 + tt)*64 + lane)*8);
            acc = __builtin_amdgcn_mfma_f32_16x16x32_bf16(a1[kc], b, acc, 0, 0, 0);
        }
#pragma unroll
        for (int kc = 0; kc < 4; ++kc) {
            short8 b = ld8(W2_pk + (size_t)((kc*8 + tt)*64 + lane)*8);
            acc = __builtin_amdgcn_mfma_f32_16x16x32_bf16(a2[kc], b, acc, 0, 0, 0);
        }
        {
            short8 b = ld8(W3_pk + (size_t)(tt*64 + lane)*8);
            acc = __builtin_amdgcn_mfma_f32_16x16x32_bf16(a3, b, acc, 0, 0, 0);
        }
        accs[tt] = acc;
    }

    const float gl[8] = { gamma[ln], gamma[16+ln], gamma[32+ln], gamma[48+ln],
                          gamma[64+ln], gamma[80+ln], gamma[96+ln], gamma[112+ln] };
    const float bl[8] = { beta[ln], beta[16+ln], beta[32+ln], beta[48+ln],
                          beta[64+ln], beta[80+ln], beta[96+ln], beta[112+ln] };
#pragma unroll
    for (int r = 0; r < 4; ++r) {
        float s = 0.f, qq = 0.f;
#pragma unroll
        for (int tt = 0; tt < 8; ++tt) {
            float u = accs[tt][r];
            s += u; qq += u*u;
        }
#pragma unroll
        for (int off = 8; off >= 1; off >>= 1) {
            s  += __shfl_xor(s, off);
            qq += __shfl_xor(qq, off);
        }
        const float mean = s * (1.f / HD);
        const float var  = qq * (1.f / HD) - mean * mean;
        const float rstd = rsqrtf(var + LN_EPS);
        const int row = row0 + quad*4 + r;
#pragma unroll
        for (int tt = 0; tt < 8; ++tt)
            out[(size_t)row*HD + tt*16 + ln] =
                (accs[tt][r] - mean) * rstd * gl[tt] + bl[tt];
    }
}

// ---------------------------------------------------------------------------
extern "C" void kernel_launch(void* const* d_in, const int* in_sizes, int n_in,
                              void* d_out, int out_size, void* d_ws, size_t ws_size,
                              hipStream_t stream)
{
    const float* src_x = (const float*)d_in[0];
    const float* dst_x = (const float*)d_in[1];
    const int*   ei    = (const int*)d_in[2];
    const float* eattr = (const float*)d_in[3];
    const float* Wsrc  = (const float*)d_in[4];
    const float* bsrc  = (const float*)d_in[5];
    const float* Wdst  = (const float*)d_in[6];
    const float* bdst  = (const float*)d_in[7];
    const float* We    = (const float*)d_in[8];
    const float* be    = (const float*)d_in[9];
    const float* Wattn = (const float*)d_in[10];
    const float* battn = (const float*)d_in[11];
    const float* Wmsg  = (const float*)d_in[12];
    const float* bmsg  = (const float*)d_in[13];
    const float* Wout  = (const float*)d_in[14];
    const float* bout  = (const float*)d_in[15];
    const float* gamma = (const float*)d_in[16];
    const float* beta  = (const float*)d_in[17];
    float* out = (float*)d_out;

    float* ws = (float*)d_ws;
    u16* srcmsgb = (u16*)(ws + 0);            // 6.4M u16
    u16* aggSb   = (u16*)(ws + 3200000);      // 6.4M u16
    u16* weab    = (u16*)(ws + 6400000);      // 1.6M u16
    u16* eas     = (u16*)(ws + 7200000);      // 16M u16 (scattered ea rows)
    float* s1    = ws + 15200000;             // 50048
    float* s2    = ws + 15250048;             // 50048
    float* Wsm   = ws + 15300096;             // 16384
    float* bsm   = ws + 15316480;             // 128
    float* WeMsg = ws + 15316608;             // 4096
    float* c2    = ws + 15320704;             // 128
    float* W3    = ws + 15320832;             // 4096
    float* bias2 = ws + 15324928;             // 128
    float* Wout1p= ws + 15325056;             // 16384
    u16* Wsrc_pk = (u16*)(ws + 15341440);     // 16384 u16
    u16* Wdst_pk = (u16*)(ws + 15349632);
    u16* Wsm_pk  = (u16*)(ws + 15357824);
    u16* W1_pk   = (u16*)(ws + 15366016);
    u16* W2_pk   = (u16*)(ws + 15374208);
    u16* We_pk   = (u16*)(ws + 15382400);     // 4096 u16
    u16* W3_pk   = (u16*)(ws + 15384448);     // 4096 u16
    int* rowptr  = (int*)(ws + 15386496);     // 50016
    int* cursor  = rowptr + 50016;            // 50016
    int* bsum    = cursor + 50016;            // 64
    int2* ev8    = (int2*)(bsum + 64);        // 500000 int2 (8B records)

    hipMemsetAsync(cursor, 0, NDST * sizeof(int), stream);

    fold1_kernel<<<162, 128, 0, stream>>>(Wsrc, bsrc, We, be, Wmsg, bmsg,
                                          Wsm, bsm, WeMsg, c2);
    fold2_kernel<<<161, 128, 0, stream>>>(WeMsg, c2, Wout, bout, W3, bias2, Wout1p);
    pack_all_kernel<<<176, 64, 0, stream>>>(Wsrc, Wdst, Wsm, Wout1p, Wout + HD*HD,
                                            We, W3,
                                            Wsrc_pk, Wdst_pk, Wsm_pk, W1_pk,
                                            W2_pk, We_pk, W3_pk);

    const int g16 = (NSRC/16 + 3) / 4;        // 782 blocks, 4 waves each

    node_gemm_kernel<<<g16, 256, 0, stream>>>(src_x, Wsrc_pk, Wsm_pk, bsrc, bsm,
                                              Wattn, s1, srcmsgb);
    dst_gemm_kernel<<<g16, 256, 0, stream>>>(dst_x, Wdst_pk, bdst, Wattn + HD, s2);

    hist_kernel<<<(NE + 255) / 256, 256, 0, stream>>>(ei, cursor);
    scan1_kernel<<<(NDST + 1023) / 1024, 1024, 0, stream>>>(cursor, rowptr, bsum);
    scan2_kernel<<<1, 64, 0, stream>>>(bsum, rowptr);
    scan3_kernel<<<(NDST + 255) / 256, 256, 0, stream>>>(bsum, rowptr, cursor);

    edge_score_kernel<<<(NE/16 + 3) / 4, 256, 0, stream>>>(
        ei, eattr, We_pk, be, Wattn, battn, s1, s2, cursor, ev8, eas);

    dst_agg_kernel<<<NDST / 4, 256, 0, stream>>>(ev8, eas, rowptr, srcmsgb,
                                                 c2, aggSb, weab);

    final_kernel<<<g16, 256, 0, stream>>>(dst_x, aggSb, weab, W1_pk, W2_pk, W3_pk,
                                          bias2, gamma, beta, out);
}

// Round 3
// 305.755 us; speedup vs baseline: 1.2696x; 1.1042x over previous
//
#include <hip/hip_runtime.h>
#include <math.h>

#define NSRC 50000
#define NDST 50000
#define NE   500000
#define HD   128
#define EDIM 32
#define LN_EPS 1e-5f

typedef __attribute__((ext_vector_type(8))) short short8;   // 8 bf16 = 4 VGPR
typedef __attribute__((ext_vector_type(4))) float f32x4;
typedef unsigned short u16;

#define TL2E 2.8853900817779268f   /* 2*log2(e) */
#define L2E  1.4426950408889634f   /* log2(e)   */

__device__ __forceinline__ float EXP2(float x) {
#if __has_builtin(__builtin_amdgcn_exp2f)
    return __builtin_amdgcn_exp2f(x);
#else
    return exp2f(x);
#endif
}
__device__ __forceinline__ float RCP(float x) {
#if __has_builtin(__builtin_amdgcn_rcpf)
    return __builtin_amdgcn_rcpf(x);
#else
    return 1.f / x;
#endif
}
__device__ __forceinline__ u16 f2b(float x) {           // f32 -> bf16 RNE
    unsigned u = __float_as_uint(x);
    return (u16)((u + 0x7FFFu + ((u >> 16) & 1u)) >> 16);
}
__device__ __forceinline__ float b2f(u16 h) {
    return __uint_as_float(((unsigned)h) << 16);
}
__device__ __forceinline__ short8 ld8(const u16* p) { return *(const short8*)p; }

// ---------------------------------------------------------------------------
// fold1: Wsm = Wsrc@Wmsg, bsm = bsrc@Wmsg + bmsg, WeMsg = We@Wmsg, c2 = be@Wmsg
// extra blocks (r >= 162) zero the histogram counters (replaces memset launch).
// ---------------------------------------------------------------------------
__global__ __launch_bounds__(128) void fold1_kernel(
    const float* __restrict__ Wsrc, const float* __restrict__ bsrc,
    const float* __restrict__ We,   const float* __restrict__ be,
    const float* __restrict__ Wmsg, const float* __restrict__ bmsg,
    float* __restrict__ Wsm, float* __restrict__ bsm,
    float* __restrict__ WeMsg, float* __restrict__ c2,
    int* __restrict__ cnt)
{
    const int j = threadIdx.x;
    const int r = blockIdx.x;
    if (r >= 162) {
        int i = (r - 162) * 128 + j;
        if (i < NDST + 16) cnt[i] = 0;
        return;
    }
    float s = 0.f;
    if (r < 128) {
        for (int k = 0; k < 128; ++k) s += Wsrc[r*HD + k] * Wmsg[k*HD + j];
        Wsm[r*HD + j] = s;
    } else if (r < 160) {
        const int rr = r - 128;
        for (int k = 0; k < 128; ++k) s += We[rr*HD + k] * Wmsg[k*HD + j];
        WeMsg[rr*HD + j] = s;
    } else if (r == 160) {
        for (int k = 0; k < 128; ++k) s += bsrc[k] * Wmsg[k*HD + j];
        bsm[j] = s + bmsg[j];
    } else {
        for (int k = 0; k < 128; ++k) s += be[k] * Wmsg[k*HD + j];
        c2[j] = s;
    }
}

// ---------------------------------------------------------------------------
// pack_all: pack f32 [K x 128] weights into bf16 MFMA B-fragment layout.
// Wsrc/Wdst/We pre-scaled by 2*log2(e) (tanh-dot exp2/rcp refactor).
// W1 = Wout1 + I computed inline. W3 = WeMsg@Wout2 and bias2 = bout + c2@Wout2
// computed inline (absorbs old fold2 launch).
// blocks: Wsrc 0-31, Wdst 32-63, Wsm 64-95, W1 96-127, W2 128-159,
//         We 160-167 (K=32), W3 168-175 (K=32, computed), bias2 176.
// ---------------------------------------------------------------------------
__global__ __launch_bounds__(64) void pack_all_kernel(
    const float* __restrict__ Wsrc, const float* __restrict__ Wdst,
    const float* __restrict__ Wsm,  const float* __restrict__ Wout,
    const float* __restrict__ We,   const float* __restrict__ WeMsg,
    const float* __restrict__ c2,   const float* __restrict__ bout,
    u16* __restrict__ Wsrc_pk, u16* __restrict__ Wdst_pk,
    u16* __restrict__ Wsm_pk,  u16* __restrict__ W1_pk,
    u16* __restrict__ W2_pk,   u16* __restrict__ We_pk,
    u16* __restrict__ W3_pk,   float* __restrict__ bias2)
{
    const int b = blockIdx.x;
    const int lane = threadIdx.x;
    const int ln = lane & 15, quad = lane >> 4;
    const float* Wout2 = Wout + HD*HD;

    if (b == 176) {                        // bias2 = bout + c2@Wout2
#pragma unroll
        for (int h = 0; h < 2; ++h) {
            const int col = lane + h*64;
            float s = 0.f;
            for (int k = 0; k < 128; ++k) s += c2[k] * Wout2[k*HD + col];
            bias2[col] = bout[col] + s;
        }
        return;
    }
    if (b >= 168) {                        // W3 = WeMsg@Wout2 (32x128), packed
        const int t = b - 168;
        const int jj = t*16 + ln;
        float sacc[8] = {0,0,0,0,0,0,0,0};
        for (int k = 0; k < 128; ++k) {
            const float w2 = Wout2[k*HD + jj];
#pragma unroll
            for (int j = 0; j < 8; ++j)
                sacc[j] = fmaf(WeMsg[(quad*8 + j)*HD + k], w2, sacc[j]);
        }
        u16 tmp[8];
#pragma unroll
        for (int j = 0; j < 8; ++j) tmp[j] = f2b(sacc[j]);
        *(short8*)(W3_pk + (size_t)(t*64 + lane)*8) = *(short8*)tmp;
        return;
    }

    const float* src; u16* dst; int lb; float scl = 1.f; bool addI = false;
    if      (b < 32)  { src = Wsrc; dst = Wsrc_pk; lb = b;       scl = TL2E; }
    else if (b < 64)  { src = Wdst; dst = Wdst_pk; lb = b - 32;  scl = TL2E; }
    else if (b < 96)  { src = Wsm;  dst = Wsm_pk;  lb = b - 64; }
    else if (b < 128) { src = Wout; dst = W1_pk;   lb = b - 96;  addI = true; }
    else if (b < 160) { src = Wout2;dst = W2_pk;   lb = b - 128; }
    else              { src = We;   dst = We_pk;   lb = b - 160; scl = TL2E; }
    const int kc = lb >> 3, t = lb & 7;
    u16 tmp[8];
#pragma unroll
    for (int j = 0; j < 8; ++j) {
        const int i = kc*32 + quad*8 + j, jj = t*16 + ln;
        float v = src[(size_t)i*HD + jj] * scl;
        if (addI && i == jj) v += 1.f;
        tmp[j] = f2b(v);
    }
    *(short8*)(dst + (size_t)(lb*64 + lane)*8) = *(short8*)tmp;
}

// ---------------------------------------------------------------------------
// mega: block-range fusion of three independent kernels:
//   [0, GN)       node path: s1 tanh-dot + srcmsgb = bf16(x@Wsm + bsm)
//   [GN, 2*GN)    dst path:  s2 tanh-dot
//   [2*GN, +HB)   hist path: cnt[dst]++ and rank[e] = old count
// ---------------------------------------------------------------------------
#define GN 782
#define HB ((NE + 255) / 256)

__global__ __launch_bounds__(256) void mega_kernel(
    const float* __restrict__ src_x, const float* __restrict__ dst_x,
    const int* __restrict__ ei,
    const u16* __restrict__ Wsrc_pk, const u16* __restrict__ Wsm_pk,
    const u16* __restrict__ Wdst_pk,
    const float* __restrict__ bsrc, const float* __restrict__ bsm,
    const float* __restrict__ bdst, const float* __restrict__ wattn,
    float* __restrict__ s1, float* __restrict__ s2,
    u16* __restrict__ srcmsgb, int* __restrict__ cnt, int* __restrict__ rank)
{
    __shared__ u16 lds[4 * 16 * HD];     // 16 KB, node path only
    const int t = threadIdx.x;
    const int blk = blockIdx.x;

    if (blk >= 2*GN) {                   // ---- hist path
        const int e = (blk - 2*GN) * 256 + t;
        if (e < NE) rank[e] = atomicAdd(&cnt[ei[NE + e]], 1);
        return;
    }

    const int w = t >> 6, lane = t & 63;
    const int ln = lane & 15, quad = lane >> 4;
    const bool is_src = (blk < GN);
    const int b = is_src ? blk : blk - GN;
    int row0 = (b * 4 + w) * 16;
    if (row0 > NSRC - 16) row0 = NSRC - 16;   // NSRC==NDST; clamp benign

    const float* xp = (is_src ? src_x : dst_x) + (size_t)(row0 + ln)*HD;
    short8 a[4];
#pragma unroll
    for (int kc = 0; kc < 4; ++kc) {
        float4 f0 = *(const float4*)(xp + kc*32 + quad*8);
        float4 f1 = *(const float4*)(xp + kc*32 + quad*8 + 4);
        u16 tb[8] = { f2b(f0.x), f2b(f0.y), f2b(f0.z), f2b(f0.w),
                      f2b(f1.x), f2b(f1.y), f2b(f1.z), f2b(f1.w) };
        a[kc] = *(short8*)tb;
    }

    const u16*   Wpk = is_src ? Wsrc_pk : Wdst_pk;
    const float* bb_ = is_src ? bsrc : bdst;
    const float* wa  = is_src ? wattn : wattn + HD;
    float* sout      = is_src ? s1 : s2;

    // ---- tanh-dot path (exp2/rcp refactor)
    float v[4] = {0.f, 0.f, 0.f, 0.f};
    float ws = 0.f;
#pragma unroll
    for (int tt = 0; tt < 8; ++tt) {
        const float bb = bb_[tt*16 + ln] * TL2E;
        const float ww = wa[tt*16 + ln];
        f32x4 acc = {bb, bb, bb, bb};
#pragma unroll
        for (int kc = 0; kc < 4; ++kc) {
            short8 bfr = ld8(Wpk + (size_t)((kc*8 + tt)*64 + lane)*8);
            acc = __builtin_amdgcn_mfma_f32_16x16x32_bf16(a[kc], bfr, acc, 0, 0, 0);
        }
        ws += ww;
#pragma unroll
        for (int r = 0; r < 4; ++r)
            v[r] = fmaf(ww, RCP(EXP2(acc[r]) + 1.f), v[r]);
    }
#pragma unroll
    for (int off = 8; off >= 1; off >>= 1) {
        ws += __shfl_xor(ws, off);
#pragma unroll
        for (int r = 0; r < 4; ++r) v[r] += __shfl_xor(v[r], off);
    }
    if (ln == 0) {
#pragma unroll
        for (int r = 0; r < 4; ++r)
            sout[row0 + quad*4 + r] = fmaf(-2.f, v[r], ws);
    }

    if (!is_src) return;

    // ---- srcmsg path (node only)
#pragma unroll
    for (int tt = 0; tt < 8; ++tt) {
        const float bs = bsm[tt*16 + ln];
        f32x4 acc = {bs, bs, bs, bs};
#pragma unroll
        for (int kc = 0; kc < 4; ++kc) {
            short8 bfr = ld8(Wsm_pk + (size_t)((kc*8 + tt)*64 + lane)*8);
            acc = __builtin_amdgcn_mfma_f32_16x16x32_bf16(a[kc], bfr, acc, 0, 0, 0);
        }
#pragma unroll
        for (int r = 0; r < 4; ++r)
            lds[w*2048 + (quad*4 + r)*HD + tt*16 + ln] = f2b(acc[r]);
    }
    __syncthreads();
#pragma unroll
    for (int r = 0; r < 4; ++r) {
        int idx = r*512 + lane*8;
        short8 val = *(short8*)(lds + w*2048 + idx);
        int row = idx >> 7, col = idx & 127;
        *(short8*)(srcmsgb + (size_t)(row0 + row)*HD + col) = val;
    }
}

// ---------------------------------------------------------------------------
// scan1: per-1024-chunk exclusive scan of cnt into rowptr, block sums to bsum
// ---------------------------------------------------------------------------
__global__ __launch_bounds__(1024) void scan1_kernel(
    const int* __restrict__ cnt, int* __restrict__ excl, int* __restrict__ bsum)
{
    __shared__ int buf[1024];
    const int t = threadIdx.x;
    const int i = blockIdx.x * 1024 + t;
    int v = (i < NDST) ? cnt[i] : 0;
    buf[t] = v;
    __syncthreads();
    for (int off = 1; off < 1024; off <<= 1) {
        int tv = (t >= off) ? buf[t - off] : 0;
        __syncthreads();
        buf[t] += tv;
        __syncthreads();
    }
    if (i < NDST) excl[i] = buf[t] - v;
    if (t == 1023) bsum[blockIdx.x] = buf[1023];
}

// ---------------------------------------------------------------------------
// scan23: merged scan2+scan3 -- every block redundantly wave-scans the 49
// chunk sums (cheap), then applies the offset to its rowptr slice.
// ---------------------------------------------------------------------------
__global__ __launch_bounds__(256) void scan23_kernel(
    const int* __restrict__ bsum, int* __restrict__ rowptr)
{
    __shared__ int pref[64];
    const int t = threadIdx.x;
    const int NB = (NDST + 1023) / 1024;     // 49
    if (t < 64) {
        int orig = (t < NB) ? bsum[t] : 0;
        int v = orig;
        for (int off = 1; off < 64; off <<= 1) {
            int u = __shfl_up(v, off);
            if (t >= off) v += u;
        }
        pref[t] = v - orig;                  // exclusive prefix
        if (blockIdx.x == 0 && t == NB - 1) rowptr[NDST] = v;  // total
    }
    __syncthreads();
    const int i = blockIdx.x * 256 + t;
    if (i < NDST) rowptr[i] += pref[i >> 10];
}

// ---------------------------------------------------------------------------
// edge_score: 16 edges / wave. Reads edge_attr f32 directly; tanh-dot in
// exp2/rcp form; score kept in log2-domain (no-max softmax is safe:
// |score| <= sum|wattn| + |battn| <= ~10). ATOMIC-FREE scatter: slot
// pos = rowptr[dst] + rank[e] (rank from hist). 16 parallel lanes (quad 0)
// each handle one edge's epilogue. Record int4 {src, e, score, 0}.
// ---------------------------------------------------------------------------
__global__ __launch_bounds__(256) void edge_score_kernel(
    const int* __restrict__ ei, const float* __restrict__ eattr,
    const u16* __restrict__ We_pk, const float* __restrict__ be,
    const float* __restrict__ wattn, const float* __restrict__ battn,
    const float* __restrict__ s1, const float* __restrict__ s2,
    const int* __restrict__ rowptr, const int* __restrict__ rank,
    int4* __restrict__ ev16)
{
    const int t = threadIdx.x;
    const int w = t >> 6, lane = t & 63;
    const int ln = lane & 15, quad = lane >> 4;
    const int e0 = (blockIdx.x * 4 + w) * 16;
    if (e0 >= NE) return;                  // NE%16==0, no partial tiles

    const float* ap = eattr + (size_t)(e0 + ln)*EDIM + quad*8;
    float4 f0 = *(const float4*)(ap);
    float4 f1 = *(const float4*)(ap + 4);
    u16 ab[8] = { f2b(f0.x), f2b(f0.y), f2b(f0.z), f2b(f0.w),
                  f2b(f1.x), f2b(f1.y), f2b(f1.z), f2b(f1.w) };
    short8 a = *(short8*)ab;

    const float* wa3 = wattn + 2*HD;
    float v[4] = {0.f, 0.f, 0.f, 0.f};
    float ws = 0.f;
#pragma unroll
    for (int tt = 0; tt < 8; ++tt) {
        const float bb = be[tt*16 + ln] * TL2E;
        const float ww = wa3[tt*16 + ln];
        f32x4 acc = {bb, bb, bb, bb};
        short8 b = ld8(We_pk + (size_t)(tt*64 + lane)*8);
        acc = __builtin_amdgcn_mfma_f32_16x16x32_bf16(a, b, acc, 0, 0, 0);
        ws += ww;
#pragma unroll
        for (int r = 0; r < 4; ++r)
            v[r] = fmaf(ww, RCP(EXP2(acc[r]) + 1.f), v[r]);
    }
#pragma unroll
    for (int off = 8; off >= 1; off >>= 1) {
        ws += __shfl_xor(ws, off);
#pragma unroll
        for (int r = 0; r < 4; ++r) v[r] += __shfl_xor(v[r], off);
    }
    // redistribute: lane ln gets the dot for edge e0+ln
    const int srcq = (ln >> 2) << 4;
    float sv0 = __shfl(v[0], srcq);
    float sv1 = __shfl(v[1], srcq);
    float sv2 = __shfl(v[2], srcq);
    float sv3 = __shfl(v[3], srcq);
    const int rr = ln & 3;
    float vlo = (rr & 1) ? sv1 : sv0;
    float vhi = (rr & 1) ? sv3 : sv2;
    float vv  = (rr & 2) ? vhi : vlo;

    if (quad == 0) {                       // 16 lanes, one edge each
        const int e = e0 + ln;
        const int srcn = ei[e];
        const int dstn = ei[NE + e];
        float sc = (fmaf(-2.f, vv, ws) + s1[srcn] + s2[dstn] + battn[0]) * L2E;
        const int pos = rowptr[dstn] + rank[e];
        ev16[pos] = make_int4(srcn, e, __float_as_int(sc), 0);
    }
}

// ---------------------------------------------------------------------------
// dst_agg: 1 wave per dst, SINGLE PASS (no-max softmax): accumulate
// unnormalized w=exp2(sc), sum(w), sum(w*msg), sum(w*ea); normalize at end.
// 4 edges in flight (el groups); msg row: 16 lanes x 16B bf16 (256B);
// ea row: 8 lanes x 16B f32 (128B = one cache line, zero over-fetch).
// ev16 prefetched one iteration ahead. Empty dst: aggSb=-c2, weab=0.
// ---------------------------------------------------------------------------
__global__ __launch_bounds__(256) void dst_agg_kernel(
    const int4* __restrict__ ev16, const int* __restrict__ rowptr,
    const u16* __restrict__ srcmsgb, const float* __restrict__ eattr,
    const float* __restrict__ c2,
    u16* __restrict__ aggSb, u16* __restrict__ weab)
{
    const int lane = threadIdx.x & 63;
    const int d = blockIdx.x * 4 + (threadIdx.x >> 6);
    const int el = lane >> 4, c = lane & 15;
    const int start = rowptr[d], end = rowptr[d + 1];

    if (start == end) {
        if (el == 0) {
            u16 z[8];
#pragma unroll
            for (int j = 0; j < 8; ++j) z[j] = f2b(-c2[c*8 + j]);
            *(short8*)(aggSb + (size_t)d*HD + c*8) = *(short8*)z;
            if (c < 8) {
                u16 zz[4] = {0,0,0,0};
                *(ushort4*)(weab + (size_t)d*EDIM + c*4) = *(ushort4*)zz;
            }
        }
        return;
    }

    float sacc = 0.f;
    float acc[8]  = {0,0,0,0,0,0,0,0};
    float wacc[4] = {0,0,0,0};

    int icur = start + el;
    bool vcur = (icur < end);
    int iicur = vcur ? icur : start;
    int4 q = ev16[iicur];

    for (int i0 = start; i0 < end; i0 += 4) {
        const float wgt = vcur ? EXP2(__int_as_float(q.z)) : 0.f;
        const int   srow = q.x;
        const int   ecur = q.y;
        // prefetch next record (clamped; harmless re-read of ev16[start])
        const int inx = i0 + 4 + el;
        vcur = (inx < end);
        iicur = vcur ? inx : start;
        q = ev16[iicur];

        sacc += wgt;
        short8 sm = ld8(srcmsgb + (size_t)srow*HD + c*8);
#pragma unroll
        for (int j = 0; j < 8; ++j)
            acc[j] = fmaf(wgt, b2f(((u16*)&sm)[j]), acc[j]);
        if (c < 8) {
            float4 f = *(const float4*)(eattr + (size_t)ecur*EDIM + c*4);
            wacc[0] = fmaf(wgt, f.x, wacc[0]);
            wacc[1] = fmaf(wgt, f.y, wacc[1]);
            wacc[2] = fmaf(wgt, f.z, wacc[2]);
            wacc[3] = fmaf(wgt, f.w, wacc[3]);
        }
    }
#pragma unroll
    for (int off = 16; off <= 32; off <<= 1) {
        sacc += __shfl_xor(sacc, off);
#pragma unroll
        for (int j = 0; j < 8; ++j) acc[j] += __shfl_xor(acc[j], off);
#pragma unroll
        for (int j = 0; j < 4; ++j) wacc[j] += __shfl_xor(wacc[j], off);
    }
    const float inv = RCP(sacc);
    if (el == 0) {
        u16 o[8];
#pragma unroll
        for (int j = 0; j < 8; ++j) o[j] = f2b(acc[j] * inv);
        *(short8*)(aggSb + (size_t)d*HD + c*8) = *(short8*)o;
        if (c < 8) {
            u16 o2[4];
#pragma unroll
            for (int j = 0; j < 4; ++j) o2[j] = f2b(wacc[j] * inv);
            *(ushort4*)(weab + (size_t)d*EDIM + c*4) = *(ushort4*)o2;
        }
    }
}

// ---------------------------------------------------------------------------
// final: out = LN(dst_x@W1p + aggSb@Wout2 + weab@W3 + bias2) * gamma + beta
// per 16 dst rows / wave; dst_x read f32 + converted in-reg.
// ---------------------------------------------------------------------------
__global__ __launch_bounds__(256) void final_kernel(
    const float* __restrict__ dst_x, const u16* __restrict__ aggSb,
    const u16* __restrict__ weab,
    const u16* __restrict__ W1_pk, const u16* __restrict__ W2_pk,
    const u16* __restrict__ W3_pk, const float* __restrict__ bias2,
    const float* __restrict__ gamma, const float* __restrict__ beta,
    float* __restrict__ out)
{
    const int t = threadIdx.x;
    const int w = t >> 6, lane = t & 63;
    const int ln = lane & 15, quad = lane >> 4;
    int row0 = (blockIdx.x * 4 + w) * 16;
    if (row0 > NDST - 16) row0 = NDST - 16;

    const float* rp = dst_x + (size_t)(row0 + ln)*HD;
    short8 a1[4], a2[4], a3;
#pragma unroll
    for (int kc = 0; kc < 4; ++kc) {
        float4 f0 = *(const float4*)(rp + kc*32 + quad*8);
        float4 f1 = *(const float4*)(rp + kc*32 + quad*8 + 4);
        u16 tb[8] = { f2b(f0.x), f2b(f0.y), f2b(f0.z), f2b(f0.w),
                      f2b(f1.x), f2b(f1.y), f2b(f1.z), f2b(f1.w) };
        a1[kc] = *(short8*)tb;
        a2[kc] = ld8(aggSb + (size_t)(row0 + ln)*HD + kc*32 + quad*8);
    }
    a3 = ld8(weab + (size_t)(row0 + ln)*EDIM + quad*8);

    f32x4 accs[8];
#pragma unroll
    for (int tt = 0; tt < 8; ++tt) {
        const float bb = bias2[tt*16 + ln];
        f32x4 acc = {bb, bb, bb, bb};
#pragma unroll
        for (int kc = 0; kc < 4; ++kc) {
            short8 b = ld8(W1_pk + (size_t)((kc*8 + tt)*64 + lane)*8);
            acc = __builtin_amdgcn_mfma_f32_16x16x32_bf16(a1[kc], b, acc, 0, 0, 0);
        }
#pragma unroll
        for (int kc = 0; kc < 4; ++kc) {
            short8 b = ld8(W2_pk + (size_t)((kc*8 + tt)*64 + lane)*8);
            acc = __builtin_amdgcn_mfma_f32_16x16x32_bf16(a2[kc], b, acc, 0, 0, 0);
        }
        {
            short8 b = ld8(W3_pk + (size_t)(tt*64 + lane)*8);
            acc = __builtin_amdgcn_mfma_f32_16x16x32_bf16(a3, b, acc, 0, 0, 0);
        }
        accs[tt] = acc;
    }

    const float gl[8] = { gamma[ln], gamma[16+ln], gamma[32+ln], gamma[48+ln],
                          gamma[64+ln], gamma[80+ln], gamma[96+ln], gamma[112+ln] };
    const float bl[8] = { beta[ln], beta[16+ln], beta[32+ln], beta[48+ln],
                          beta[64+ln], beta[80+ln], beta[96+ln], beta[112+ln] };
#pragma unroll
    for (int r = 0; r < 4; ++r) {
        float s = 0.f, qq = 0.f;
#pragma unroll
        for (int tt = 0; tt < 8; ++tt) {
            float u = accs[tt][r];
            s += u; qq += u*u;
        }
#pragma unroll
        for (int off = 8; off >= 1; off >>= 1) {
            s  += __shfl_xor(s, off);
            qq += __shfl_xor(qq, off);
        }
        const float mean = s * (1.f / HD);
        const float var  = qq * (1.f / HD) - mean * mean;
        const float rstd = rsqrtf(var + LN_EPS);
        const int row = row0 + quad*4 + r;
#pragma unroll
        for (int tt = 0; tt < 8; ++tt)
            out[(size_t)row*HD + tt*16 + ln] =
                (accs[tt][r] - mean) * rstd * gl[tt] + bl[tt];
    }
}

// ---------------------------------------------------------------------------
extern "C" void kernel_launch(void* const* d_in, const int* in_sizes, int n_in,
                              void* d_out, int out_size, void* d_ws, size_t ws_size,
                              hipStream_t stream)
{
    const float* src_x = (const float*)d_in[0];
    const float* dst_x = (const float*)d_in[1];
    const int*   ei    = (const int*)d_in[2];
    const float* eattr = (const float*)d_in[3];
    const float* Wsrc  = (const float*)d_in[4];
    const float* bsrc  = (const float*)d_in[5];
    const float* Wdst  = (const float*)d_in[6];
    const float* bdst  = (const float*)d_in[7];
    const float* We    = (const float*)d_in[8];
    const float* be    = (const float*)d_in[9];
    const float* Wattn = (const float*)d_in[10];
    const float* battn = (const float*)d_in[11];
    const float* Wmsg  = (const float*)d_in[12];
    const float* bmsg  = (const float*)d_in[13];
    const float* Wout  = (const float*)d_in[14];
    const float* bout  = (const float*)d_in[15];
    const float* gamma = (const float*)d_in[16];
    const float* beta  = (const float*)d_in[17];
    float* out = (float*)d_out;

    float* ws = (float*)d_ws;
    u16* srcmsgb = (u16*)(ws + 0);            // 6.4M u16
    u16* aggSb   = (u16*)(ws + 3200000);      // 6.4M u16
    u16* weab    = (u16*)(ws + 6400000);      // 1.6M u16
    float* s1    = ws + 7200000;              // 50048
    float* s2    = ws + 7250048;              // 50048
    float* Wsm   = ws + 7300096;              // 16384
    float* bsm   = ws + 7316480;              // 128
    float* WeMsg = ws + 7316608;              // 4096
    float* c2    = ws + 7320704;              // 128
    float* bias2 = ws + 7320832;              // 128
    u16* Wsrc_pk = (u16*)(ws + 7320960);      // 16384 u16
    u16* Wdst_pk = (u16*)(ws + 7329152);
    u16* Wsm_pk  = (u16*)(ws + 7337344);
    u16* W1_pk   = (u16*)(ws + 7345536);
    u16* W2_pk   = (u16*)(ws + 7353728);
    u16* We_pk   = (u16*)(ws + 7361920);      // 4096 u16
    u16* W3_pk   = (u16*)(ws + 7363968);      // 4096 u16
    int* rowptr  = (int*)(ws + 7366016);      // 50016
    int* cnt     = (int*)(ws + 7416032);      // 50016
    int* bsum    = (int*)(ws + 7466048);      // 64
    int* rank    = (int*)(ws + 7466112);      // 500000
    int4* ev16   = (int4*)(ws + 7966112);     // 500000 int4 (16B-aligned)

    fold1_kernel<<<553, 128, 0, stream>>>(Wsrc, bsrc, We, be, Wmsg, bmsg,
                                          Wsm, bsm, WeMsg, c2, cnt);
    pack_all_kernel<<<177, 64, 0, stream>>>(Wsrc, Wdst, Wsm, Wout, We, WeMsg,
                                            c2, bout,
                                            Wsrc_pk, Wdst_pk, Wsm_pk, W1_pk,
                                            W2_pk, We_pk, W3_pk, bias2);

    mega_kernel<<<2*GN + HB, 256, 0, stream>>>(
        src_x, dst_x, ei, Wsrc_pk, Wsm_pk, Wdst_pk,
        bsrc, bsm, bdst, Wattn, s1, s2, srcmsgb, cnt, rank);

    scan1_kernel<<<(NDST + 1023) / 1024, 1024, 0, stream>>>(cnt, rowptr, bsum);
    scan23_kernel<<<(NDST + 255) / 256, 256, 0, stream>>>(bsum, rowptr);

    edge_score_kernel<<<(NE/16 + 3) / 4, 256, 0, stream>>>(
        ei, eattr, We_pk, be, Wattn, battn, s1, s2, rowptr, rank, ev16);

    dst_agg_kernel<<<NDST / 4, 256, 0, stream>>>(ev16, rowptr, srcmsgb,
                                                 eattr, c2, aggSb, weab);

    final_kernel<<<GN, 256, 0, stream>>>(dst_x, aggSb, weab, W1_pk, W2_pk, W3_pk,
                                         bias2, gamma, beta, out);
}